// Round 1
// baseline (353.518 us; speedup 1.0000x reference)
//
#include <hip/hip_runtime.h>

typedef float f32x4 __attribute__((ext_vector_type(4)));
typedef __bf16 bf16x8 __attribute__((ext_vector_type(8)));
typedef unsigned short u16x4 __attribute__((ext_vector_type(4)));
typedef unsigned short u16x8 __attribute__((ext_vector_type(8)));

__device__ __forceinline__ unsigned short f2bf(float f){
  union { float f; unsigned u; } v; v.f = f;
  unsigned u = v.u;
  return (unsigned short)((u + 0x7fffu + ((u >> 16) & 1u)) >> 16);
}
__device__ __forceinline__ float bf2f(unsigned short h){
  union { unsigned u; float f; } v; v.u = ((unsigned)h) << 16; return v.f;
}

// ---------------- init: Aneg = -M, S = I, P = -M ----------------
__global__ __launch_bounds__(256) void k_init(const float* __restrict__ M, float* __restrict__ An,
                                              float* __restrict__ S, float* __restrict__ P){
  int idx = blockIdx.x * 256 + threadIdx.x;   // 512*512 total
  float a = -M[idx];
  An[idx] = a; P[idx] = a;
  int i = idx >> 9, j = idx & 511;
  S[idx] = (i == j) ? 1.0f : 0.0f;
}

// ---------------- 512x512x512 split-bf16 MFMA GEMM pair ----------------
// z=0: C0 = base(mode0) + A0*B0   (mode 0: none, 1: +I, 2: +D0)
// z=1: C1 = A1*B1
__global__ __launch_bounds__(256) void k_spm(
    const float* __restrict__ A0, const float* __restrict__ B0,
    const float* __restrict__ D0, float* __restrict__ C0, int mode0,
    const float* __restrict__ A1, const float* __restrict__ B1, float* __restrict__ C1)
{
  const float *A, *B, *D; float* C; int mode;
  if (blockIdx.z == 0){ A=A0; B=B0; D=D0; C=C0; mode=mode0; }
  else { A=A1; B=B1; D=nullptr; C=C1; mode=0; }

  __shared__ unsigned short Ah[64*64], Al[64*64], Bh[64*64], Bl[64*64];

  int tid = threadIdx.x;
  int lane = tid & 63, wave = tid >> 6;
  int wm = wave >> 1, wn = wave & 1;
  int i0 = blockIdx.y * 64, j0 = blockIdx.x * 64;

  f32x4 acc[2][2] = {};

  for (int k0 = 0; k0 < 512; k0 += 64){
    // A staging: row-major direct, split into hi/lo bf16, XOR-swizzled
    #pragma unroll
    for (int j = 0; j < 4; ++j){
      int p = tid + j*256;
      int row = p >> 4, kq = p & 15;
      f32x4 v = *reinterpret_cast<const f32x4*>(A + (i0+row)*512 + k0 + kq*4);
      u16x4 hi, lo;
      #pragma unroll
      for (int e = 0; e < 4; ++e){
        unsigned short h = f2bf(v[e]);
        hi[e] = h;
        lo[e] = f2bf(v[e] - bf2f(h));
      }
      int off = row*128 + ((kq*8) ^ ((row & 7) << 4));
      *reinterpret_cast<u16x4*>((char*)Ah + off) = hi;
      *reinterpret_cast<u16x4*>((char*)Al + off) = lo;
    }
    // B staging: in-flight transpose to [n][k]
    {
      int n = tid & 63, kg = tid >> 6;
      #pragma unroll
      for (int q4 = 0; q4 < 4; ++q4){
        u16x4 hi, lo;
        #pragma unroll
        for (int e = 0; e < 4; ++e){
          float f = B[(k0 + kg*16 + q4*4 + e)*512 + j0 + n];
          unsigned short h = f2bf(f);
          hi[e] = h; lo[e] = f2bf(f - bf2f(h));
        }
        int kbyte = (kg*16 + q4*4) * 2;
        int off = n*128 + (kbyte ^ ((n & 7) << 4));
        *reinterpret_cast<u16x4*>((char*)Bh + off) = hi;
        *reinterpret_cast<u16x4*>((char*)Bl + off) = lo;
      }
    }
    __syncthreads();
    #pragma unroll
    for (int kk = 0; kk < 2; ++kk){
      int kb = (kk*32 + (lane >> 4)*8) * 2;
      bf16x8 ah[2], al2[2], bh[2], bl2[2];
      #pragma unroll
      for (int m = 0; m < 2; ++m){
        int row = wm*32 + m*16 + (lane & 15);
        int off = row*128 + (kb ^ ((row & 7) << 4));
        ah[m]  = *reinterpret_cast<const bf16x8*>((char*)Ah + off);
        al2[m] = *reinterpret_cast<const bf16x8*>((char*)Al + off);
      }
      #pragma unroll
      for (int n = 0; n < 2; ++n){
        int row = wn*32 + n*16 + (lane & 15);
        int off = row*128 + (kb ^ ((row & 7) << 4));
        bh[n]  = *reinterpret_cast<const bf16x8*>((char*)Bh + off);
        bl2[n] = *reinterpret_cast<const bf16x8*>((char*)Bl + off);
      }
      #pragma unroll
      for (int m = 0; m < 2; ++m)
        #pragma unroll
        for (int n = 0; n < 2; ++n){
          acc[m][n] = __builtin_amdgcn_mfma_f32_16x16x32_bf16(ah[m],  bh[n],  acc[m][n], 0,0,0);
          acc[m][n] = __builtin_amdgcn_mfma_f32_16x16x32_bf16(ah[m],  bl2[n], acc[m][n], 0,0,0);
          acc[m][n] = __builtin_amdgcn_mfma_f32_16x16x32_bf16(al2[m], bh[n],  acc[m][n], 0,0,0);
        }
    }
    __syncthreads();
  }
  #pragma unroll
  for (int m = 0; m < 2; ++m)
    #pragma unroll
    for (int n = 0; n < 2; ++n)
      #pragma unroll
      for (int r = 0; r < 4; ++r){
        int i = i0 + wm*32 + m*16 + (lane >> 4)*4 + r;
        int j = j0 + wn*32 + n*16 + (lane & 15);
        float base = 0.f;
        if (mode == 1) base = (i == j) ? 1.0f : 0.0f;
        else if (mode == 2) base = D[i*512 + j];
        C[i*512 + j] = base + acc[m][n][r];
      }
}

// ---------------- Tt[j][i] = sum_k S[k][j] * W[k][i], bf16 output ----------------
__global__ __launch_bounds__(256) void k_T(const float* __restrict__ W, const float* __restrict__ S,
                                           unsigned short* __restrict__ Tt)
{
  __shared__ unsigned short Ah[64*64], Al[64*64], Bh[64*64], Bl[64*64];
  int tid = threadIdx.x;
  int lane = tid & 63, wave = tid >> 6;
  int wm = wave >> 1, wn = wave & 1;
  int j0 = blockIdx.y * 64;   // Tt row   (0..511)
  int i0 = blockIdx.x * 64;   // Tt col   (0..1023)

  f32x4 acc[2][2] = {};
  for (int k0 = 0; k0 < 512; k0 += 64){
    {   // A'[j][k] = S[k][j]  (transpose staging)
      int jr = tid & 63, kg = tid >> 6;
      #pragma unroll
      for (int q4 = 0; q4 < 4; ++q4){
        u16x4 hi, lo;
        #pragma unroll
        for (int e = 0; e < 4; ++e){
          float f = S[(k0 + kg*16 + q4*4 + e)*512 + j0 + jr];
          unsigned short h = f2bf(f);
          hi[e] = h; lo[e] = f2bf(f - bf2f(h));
        }
        int kbyte = (kg*16 + q4*4)*2;
        int off = jr*128 + (kbyte ^ ((jr & 7) << 4));
        *reinterpret_cast<u16x4*>((char*)Ah + off) = hi;
        *reinterpret_cast<u16x4*>((char*)Al + off) = lo;
      }
    }
    {   // B'[i][k] = W[k][i]  (transpose staging)
      int nr = tid & 63, kg = tid >> 6;
      #pragma unroll
      for (int q4 = 0; q4 < 4; ++q4){
        u16x4 hi, lo;
        #pragma unroll
        for (int e = 0; e < 4; ++e){
          float f = W[(k0 + kg*16 + q4*4 + e)*1024 + i0 + nr];
          unsigned short h = f2bf(f);
          hi[e] = h; lo[e] = f2bf(f - bf2f(h));
        }
        int kbyte = (kg*16 + q4*4)*2;
        int off = nr*128 + (kbyte ^ ((nr & 7) << 4));
        *reinterpret_cast<u16x4*>((char*)Bh + off) = hi;
        *reinterpret_cast<u16x4*>((char*)Bl + off) = lo;
      }
    }
    __syncthreads();
    #pragma unroll
    for (int kk = 0; kk < 2; ++kk){
      int kb = (kk*32 + (lane >> 4)*8) * 2;
      bf16x8 ah[2], al2[2], bh[2], bl2[2];
      #pragma unroll
      for (int m = 0; m < 2; ++m){
        int row = wm*32 + m*16 + (lane & 15);
        int off = row*128 + (kb ^ ((row & 7) << 4));
        ah[m]  = *reinterpret_cast<const bf16x8*>((char*)Ah + off);
        al2[m] = *reinterpret_cast<const bf16x8*>((char*)Al + off);
      }
      #pragma unroll
      for (int n = 0; n < 2; ++n){
        int row = wn*32 + n*16 + (lane & 15);
        int off = row*128 + (kb ^ ((row & 7) << 4));
        bh[n]  = *reinterpret_cast<const bf16x8*>((char*)Bh + off);
        bl2[n] = *reinterpret_cast<const bf16x8*>((char*)Bl + off);
      }
      #pragma unroll
      for (int m = 0; m < 2; ++m)
        #pragma unroll
        for (int n = 0; n < 2; ++n){
          acc[m][n] = __builtin_amdgcn_mfma_f32_16x16x32_bf16(ah[m],  bh[n],  acc[m][n], 0,0,0);
          acc[m][n] = __builtin_amdgcn_mfma_f32_16x16x32_bf16(ah[m],  bl2[n], acc[m][n], 0,0,0);
          acc[m][n] = __builtin_amdgcn_mfma_f32_16x16x32_bf16(al2[m], bh[n],  acc[m][n], 0,0,0);
        }
    }
    __syncthreads();
  }
  #pragma unroll
  for (int m = 0; m < 2; ++m)
    #pragma unroll
    for (int n = 0; n < 2; ++n)
      #pragma unroll
      for (int r = 0; r < 4; ++r){
        int j = j0 + wm*32 + m*16 + (lane >> 4)*4 + r;
        int i = i0 + wn*32 + n*16 + (lane & 15);
        Tt[j*1024 + i] = f2bf(acc[m][n][r]);
      }
}

// ---------------- Y[16384][512] = X[16384][1024] * Tt^T  (bf16 MFMA) ----------------
__global__ __launch_bounds__(256) void k_gemm(const float* __restrict__ X,
                                              const unsigned short* __restrict__ Tt,
                                              float* __restrict__ Y)
{
  __shared__ unsigned short As_[128*64];  // [row][k] swizzled bf16
  __shared__ unsigned short Bs_[128*64];  // [n][k]  swizzled bf16
  int tid = threadIdx.x;
  int lane = tid & 63, wave = tid >> 6;
  int wm = wave >> 1, wn = wave & 1;
  int m0 = blockIdx.y * 128, n0 = blockIdx.x * 128;

  f32x4 acc[4][4] = {};

  for (int kt = 0; kt < 1024; kt += 64){
    // A stage: f32 -> bf16 convert, swizzled ds_write
    #pragma unroll
    for (int j = 0; j < 8; ++j){
      int p = tid + j*256;
      int row = p >> 4, kq = p & 15;
      f32x4 v = *reinterpret_cast<const f32x4*>(X + (size_t)(m0+row)*1024 + kt + kq*4);
      u16x4 h;
      #pragma unroll
      for (int e = 0; e < 4; ++e) h[e] = f2bf(v[e]);
      int off = row*128 + ((kq*8) ^ ((row & 7) << 4));
      *reinterpret_cast<u16x4*>((char*)As_ + off) = h;
    }
    // B stage: bf16 copy (Tt is [n][k] already), swizzled
    #pragma unroll
    for (int j = 0; j < 4; ++j){
      int p16 = tid + j*256;              // 16-byte granule index
      int n = p16 >> 3, q16 = p16 & 7;
      u16x8 b = *reinterpret_cast<const u16x8*>(Tt + (n0+n)*1024 + kt + q16*8);
      int off = n*128 + ((q16*16) ^ ((n & 7) << 4));
      *reinterpret_cast<u16x8*>((char*)Bs_ + off) = b;
    }
    __syncthreads();
    #pragma unroll
    for (int kk = 0; kk < 2; ++kk){
      int kb = (kk*32 + (lane >> 4)*8) * 2;
      bf16x8 af[4], bfr[4];
      #pragma unroll
      for (int m = 0; m < 4; ++m){
        int row = wm*64 + m*16 + (lane & 15);
        af[m] = *reinterpret_cast<const bf16x8*>((char*)As_ + row*128 + (kb ^ ((row & 7) << 4)));
      }
      #pragma unroll
      for (int n = 0; n < 4; ++n){
        int row = wn*64 + n*16 + (lane & 15);
        bfr[n] = *reinterpret_cast<const bf16x8*>((char*)Bs_ + row*128 + (kb ^ ((row & 7) << 4)));
      }
      #pragma unroll
      for (int m = 0; m < 4; ++m)
        #pragma unroll
        for (int n = 0; n < 4; ++n)
          acc[m][n] = __builtin_amdgcn_mfma_f32_16x16x32_bf16(af[m], bfr[n], acc[m][n], 0,0,0);
    }
    __syncthreads();
  }
  #pragma unroll
  for (int m = 0; m < 4; ++m)
    #pragma unroll
    for (int n = 0; n < 4; ++n)
      #pragma unroll
      for (int r = 0; r < 4; ++r){
        int row = m0 + wm*64 + m*16 + (lane >> 4)*4 + r;
        int col = n0 + wn*64 + n*16 + (lane & 15);
        Y[(size_t)row*512 + col] = acc[m][n][r];
      }
}

extern "C" void kernel_launch(void* const* d_in, const int* in_sizes, int n_in,
                              void* d_out, int out_size, void* d_ws, size_t ws_size,
                              hipStream_t stream) {
  const float* x = (const float*)d_in[0];   // [16384][1024]
  const float* W = (const float*)d_in[1];   // [512][1024]
  const float* M = (const float*)d_in[2];   // [512][512]
  float* y = (float*)d_out;                 // [16384][512]

  float* An = (float*)d_ws;                 // -M
  float* Sa = An + 512*512;
  float* Pa = Sa + 512*512;
  float* Sb = Pa + 512*512;
  float* Pb = Sb + 512*512;
  unsigned short* Tt = (unsigned short*)(Pb + 512*512);  // [512][1024] bf16

  dim3 blk(256);
  dim3 g2(8, 8, 2), g1(8, 8, 1);

  k_init<<<1024, blk, 0, stream>>>(M, An, Sa, Pa);                 // S1=I, P1=-M
  // chain: 1 ->D 2 ->I 3 ->D 6 ->D 12 ->D 24 ->I 25 ->D 50 ->D 100 ->I 101
  k_spm<<<g2, blk, 0, stream>>>(Sa, Pa, Sa, Sb, 2,  Pa, Pa, Pb);   // S2,P2 -> b
  k_spm<<<g2, blk, 0, stream>>>(An, Sb, nullptr, Sa, 1,  Pb, An, Pa); // S3,P3 -> a
  k_spm<<<g2, blk, 0, stream>>>(Sa, Pa, Sa, Sb, 2,  Pa, Pa, Pb);   // S6  -> b
  k_spm<<<g2, blk, 0, stream>>>(Sb, Pb, Sb, Sa, 2,  Pb, Pb, Pa);   // S12 -> a
  k_spm<<<g2, blk, 0, stream>>>(Sa, Pa, Sa, Sb, 2,  Pa, Pa, Pb);   // S24 -> b
  k_spm<<<g2, blk, 0, stream>>>(An, Sb, nullptr, Sa, 1,  Pb, An, Pa); // S25 -> a
  k_spm<<<g2, blk, 0, stream>>>(Sa, Pa, Sa, Sb, 2,  Pa, Pa, Pb);   // S50 -> b
  k_spm<<<g2, blk, 0, stream>>>(Sb, Pb, Sb, Sa, 2,  Pb, Pb, Pa);   // S100 -> a
  k_spm<<<g1, blk, 0, stream>>>(An, Sa, nullptr, Sb, 1,  nullptr, nullptr, nullptr); // S101 -> Sb
  k_T   <<<dim3(16, 8), blk, 0, stream>>>(W, Sb, Tt);
  k_gemm<<<dim3(4, 128), blk, 0, stream>>>(x, Tt, y);
}